// Round 1
// baseline (201.849 us; speedup 1.0000x reference)
//
#include <hip/hip_runtime.h>
#include <hip/hip_bf16.h>

#define N_ROWS 8192
#define H_DIM  1024
#define NUM_CLS 64
#define BM 128
#define BN 128
#define BK 64
#define NCHUNK 8                                   // column chunks (grid dim)
#define TILES_PER_CHUNK (N_ROWS / NCHUNK / BN)     // 8
#define NPART (NCHUNK * 2)                         // chunk x wave-col partials

typedef __bf16 bf16x8 __attribute__((ext_vector_type(8)));
typedef float  f32x4  __attribute__((ext_vector_type(4)));

__device__ __forceinline__ float fast_exp2(float x) {
    float r;
    asm("v_exp_f32 %0, %1" : "=v"(r) : "v"(x));
    return r;
}

__device__ __forceinline__ void async_copy16(void* lds, const void* g) {
    __builtin_amdgcn_global_load_lds(
        (const __attribute__((address_space(1))) void*)g,
        (__attribute__((address_space(3))) void*)lds, 16, 0, 0);
}

// ---------------- Kernel 1: row-normalize fp32 -> bf16 ----------------
__global__ __launch_bounds__(256) void norm_kernel(const float* __restrict__ in,
                                                   ushort* __restrict__ out) {
    const int row = blockIdx.x, tid = threadIdx.x;
    const float4 v = reinterpret_cast<const float4*>(in + (size_t)row * H_DIM)[tid];
    float ss = v.x * v.x + v.y * v.y + v.z * v.z + v.w * v.w;
#pragma unroll
    for (int d = 1; d < 64; d <<= 1) ss += __shfl_xor(ss, d, 64);
    __shared__ float sred[4];
    const int lane = tid & 63, wid = tid >> 6;
    if (lane == 0) sred[wid] = ss;
    __syncthreads();
    const float tot = sred[0] + sred[1] + sred[2] + sred[3];
    const float inv = 1.0f / fmaxf(sqrtf(tot), 1e-12f);
    __hip_bfloat16 o0 = __float2bfloat16(v.x * inv);
    __hip_bfloat16 o1 = __float2bfloat16(v.y * inv);
    __hip_bfloat16 o2 = __float2bfloat16(v.z * inv);
    __hip_bfloat16 o3 = __float2bfloat16(v.w * inv);
    ushort4 o;
    o.x = *reinterpret_cast<ushort*>(&o0);
    o.y = *reinterpret_cast<ushort*>(&o1);
    o.z = *reinterpret_cast<ushort*>(&o2);
    o.w = *reinterpret_cast<ushort*>(&o3);
    reinterpret_cast<ushort4*>(out + (size_t)row * H_DIM)[tid] = o;
}

// ---- Kernel 2: fused Gram(x x^T) + exp + masked row-sum partials ----
// grid = (NCHUNK, N/BM); block = 256 (4 waves, 2x2 wave grid)
__global__ __launch_bounds__(256, 2)
void simloss_kernel(const ushort* __restrict__ xb, const int* __restrict__ labels,
                    float* __restrict__ ppos, float* __restrict__ pall) {
    __shared__ __align__(16) ushort As[BM * BK];
    __shared__ __align__(16) ushort Bs[BN * BK];

    const int chunk = blockIdx.x;
    const int row0  = blockIdx.y * BM;
    const int tid   = threadIdx.x;
    const int lane  = tid & 63;
    const int wid   = tid >> 6;
    const int wr = wid >> 1, wc = wid & 1;
    const int l15 = lane & 15, lq = lane >> 4;

    // staging geometry: segment = 1024B = 8 rows x 64 bf16; 16 segs per tile
    const int srow  = lane >> 3;   // row within segment (0..7)
    const int pslot = lane & 7;    // physical 16B slot within row

    // labels for the 16 rows this lane accumulates (fixed per block)
    int lab_r[16];
#pragma unroll
    for (int m = 0; m < 4; ++m)
#pragma unroll
        for (int r = 0; r < 4; ++r)
            lab_r[m * 4 + r] = labels[row0 + wr * 64 + m * 16 + lq * 4 + r];

    float rs_pos[16], rs_all[16];
#pragma unroll
    for (int i = 0; i < 16; ++i) { rs_pos[i] = 0.f; rs_all[i] = 0.f; }

    for (int ct = 0; ct < TILES_PER_CHUNK; ++ct) {
        const int col0 = chunk * (N_ROWS / NCHUNK) + ct * BN;
        f32x4 acc[4][4];
#pragma unroll
        for (int m = 0; m < 4; ++m)
#pragma unroll
            for (int n = 0; n < 4; ++n) acc[m][n] = (f32x4){0.f, 0.f, 0.f, 0.f};

        for (int k0 = 0; k0 < H_DIM; k0 += BK) {
            __syncthreads();   // previous tile's LDS reads complete
#pragma unroll
            for (int i = 0; i < 4; ++i) {
                const int seg = wid * 4 + i;
                const int row = seg * 8 + srow;
                const int lslot = pslot ^ (row & 7);   // pre-swizzled source (rule #21)
                async_copy16(&As[seg * 512],
                             &xb[(size_t)(row0 + row) * H_DIM + k0 + lslot * 8]);
                async_copy16(&Bs[seg * 512],
                             &xb[(size_t)(col0 + row) * H_DIM + k0 + lslot * 8]);
            }
            __syncthreads();   // compiler drains vmcnt before s_barrier
#pragma unroll
            for (int kh = 0; kh < 2; ++kh) {
                bf16x8 af[4], bfv[4];
#pragma unroll
                for (int m = 0; m < 4; ++m) {
                    const int row = wr * 64 + m * 16 + l15;
                    const int ps = (kh * 4 + lq) ^ (row & 7);
                    af[m] = *reinterpret_cast<const bf16x8*>(&As[row * 64 + ps * 8]);
                }
#pragma unroll
                for (int n = 0; n < 4; ++n) {
                    const int row = wc * 64 + n * 16 + l15;
                    const int ps = (kh * 4 + lq) ^ (row & 7);
                    bfv[n] = *reinterpret_cast<const bf16x8*>(&Bs[row * 64 + ps * 8]);
                }
#pragma unroll
                for (int m = 0; m < 4; ++m)
#pragma unroll
                    for (int n = 0; n < 4; ++n)
                        acc[m][n] = __builtin_amdgcn_mfma_f32_16x16x32_bf16(
                            af[m], bfv[n], acc[m][n], 0, 0, 0);
            }
        }

        // epilogue: exp + masked accumulate into per-row partial sums
#pragma unroll
        for (int n = 0; n < 4; ++n) {
            const int colg = col0 + wc * 64 + n * 16 + l15;
            const int lab_c = labels[colg];
#pragma unroll
            for (int m = 0; m < 4; ++m) {
#pragma unroll
                for (int r = 0; r < 4; ++r) {
                    const int rowg = row0 + wr * 64 + m * 16 + lq * 4 + r;
                    const float e = fast_exp2(acc[m][n][r] * 14.4269504088896340736f);
                    const bool notself = (colg != rowg);
                    rs_all[m * 4 + r] += notself ? e : 0.f;
                    rs_pos[m * 4 + r] += (notself && (lab_c == lab_r[m * 4 + r])) ? e : 0.f;
                }
            }
        }
    }

    // reduce across the 16 lanes of each quarter-group; write partials
#pragma unroll
    for (int i = 0; i < 16; ++i) {
        float p = rs_pos[i], a = rs_all[i];
#pragma unroll
        for (int d = 1; d < 16; d <<= 1) {
            p += __shfl_xor(p, d, 64);
            a += __shfl_xor(a, d, 64);
        }
        if (l15 == 0) {
            const int m = i >> 2, r = i & 3;
            const int rowg = row0 + wr * 64 + m * 16 + lq * 4 + r;
            const int part = chunk * 2 + wc;   // distinct partial per wave-column!
            ppos[(size_t)part * N_ROWS + rowg] = p;
            pall[(size_t)part * N_ROWS + rowg] = a;
        }
    }
}

// ---------------- Kernel 3: finalize ----------------
__global__ __launch_bounds__(256)
void finalize_kernel(const int* __restrict__ labels, const float* __restrict__ ppos,
                     const float* __restrict__ pall, float* __restrict__ out) {
    __shared__ int hist[NUM_CLS];
    __shared__ float sred[4];
    __shared__ int scnt[4];
    const int tid = threadIdx.x;
    if (tid < NUM_CLS) hist[tid] = 0;
    __syncthreads();
    for (int i = tid; i < N_ROWS; i += 256) atomicAdd(&hist[labels[i]], 1);
    __syncthreads();
    float lsum = 0.f;
    int vcnt = 0;
    for (int i = tid; i < N_ROWS; i += 256) {
        float p = 0.f, a = 0.f;
#pragma unroll
        for (int c = 0; c < NPART; ++c) {
            p += ppos[(size_t)c * N_ROWS + i];
            a += pall[(size_t)c * N_ROWS + i];
        }
        const int cnt = hist[labels[i]] - 1;
        if (cnt > 0) {
            lsum += logf(a) - logf(p) + logf((float)cnt);
            vcnt += 1;
        }
    }
    const int lane = tid & 63, wid = tid >> 6;
#pragma unroll
    for (int d = 1; d < 64; d <<= 1) {
        lsum += __shfl_xor(lsum, d, 64);
        vcnt += __shfl_xor(vcnt, d, 64);
    }
    if (lane == 0) { sred[wid] = lsum; scnt[wid] = vcnt; }
    __syncthreads();
    if (tid == 0) {
        float L = sred[0] + sred[1] + sred[2] + sred[3];
        int   C = scnt[0] + scnt[1] + scnt[2] + scnt[3];
        out[0] = L / (float)C;
    }
}

extern "C" void kernel_launch(void* const* d_in, const int* in_sizes, int n_in,
                              void* d_out, int out_size, void* d_ws, size_t ws_size,
                              hipStream_t stream) {
    const float* emb   = (const float*)d_in[0];
    const int* labels  = (const int*)d_in[1];
    float* out         = (float*)d_out;
    char* ws           = (char*)d_ws;

    ushort* xb  = (ushort*)ws;                                   // 16 MB bf16 normalized
    float* ppos = (float*)(ws + (size_t)N_ROWS * H_DIM * 2);     // NPART*N floats
    float* pall = ppos + (size_t)NPART * N_ROWS;                 // NPART*N floats

    norm_kernel<<<N_ROWS, 256, 0, stream>>>(emb, xb);
    simloss_kernel<<<dim3(NCHUNK, N_ROWS / BM), 256, 0, stream>>>(xb, labels, ppos, pall);
    finalize_kernel<<<1, 256, 0, stream>>>(labels, ppos, pall, out);
}

// Round 2
// 142.363 us; speedup vs baseline: 1.4179x; 1.4179x over previous
//
#include <hip/hip_runtime.h>
#include <hip/hip_bf16.h>

#define N_ROWS 8192
#define H_DIM  1024
#define NUM_CLS 64
#define BM 128
#define BN 128
#define BK 64
#define NBLK (N_ROWS / BM)          // 64 panels
#define NPAIR (NBLK * (NBLK + 1) / 2)  // 2080 upper-triangle blocks

typedef __bf16 bf16x8 __attribute__((ext_vector_type(8)));
typedef float  f32x4  __attribute__((ext_vector_type(4)));

__device__ __forceinline__ float fast_exp2(float x) {
    float r;
    asm("v_exp_f32 %0, %1" : "=v"(r) : "v"(x));
    return r;
}

__device__ __forceinline__ void async_copy16(void* lds, const void* g) {
    __builtin_amdgcn_global_load_lds(
        (const __attribute__((address_space(1))) void*)g,
        (__attribute__((address_space(3))) void*)lds, 16, 0, 0);
}

// ---------------- Kernel 1: row-normalize fp32 -> bf16 ----------------
__global__ __launch_bounds__(256) void norm_kernel(const float* __restrict__ in,
                                                   ushort* __restrict__ out) {
    const int row = blockIdx.x, tid = threadIdx.x;
    const float4 v = reinterpret_cast<const float4*>(in + (size_t)row * H_DIM)[tid];
    float ss = v.x * v.x + v.y * v.y + v.z * v.z + v.w * v.w;
#pragma unroll
    for (int d = 1; d < 64; d <<= 1) ss += __shfl_xor(ss, d, 64);
    __shared__ float sred[4];
    const int lane = tid & 63, wid = tid >> 6;
    if (lane == 0) sred[wid] = ss;
    __syncthreads();
    const float tot = sred[0] + sred[1] + sred[2] + sred[3];
    const float inv = 1.0f / fmaxf(sqrtf(tot), 1e-12f);
    __hip_bfloat16 o0 = __float2bfloat16(v.x * inv);
    __hip_bfloat16 o1 = __float2bfloat16(v.y * inv);
    __hip_bfloat16 o2 = __float2bfloat16(v.z * inv);
    __hip_bfloat16 o3 = __float2bfloat16(v.w * inv);
    ushort4 o;
    o.x = *reinterpret_cast<ushort*>(&o0);
    o.y = *reinterpret_cast<ushort*>(&o1);
    o.z = *reinterpret_cast<ushort*>(&o2);
    o.w = *reinterpret_cast<ushort*>(&o3);
    reinterpret_cast<ushort4*>(out + (size_t)row * H_DIM)[tid] = o;
}

// ---- Kernel 2: symmetric fused Gram + exp + masked row/col partials ----
// grid = NPAIR (upper-triangle 128x128 blocks); block = 256 (4 waves, 2x2)
__global__ __launch_bounds__(256, 2)
void simloss_kernel(const ushort* __restrict__ xb, const int* __restrict__ labels,
                    float* __restrict__ ppos, float* __restrict__ pall) {
    __shared__ __align__(16) ushort As[BM * BK];
    __shared__ __align__(16) ushort Bs[BN * BK];

    // decode linear bid -> (I, J) with I <= J, row-major over the triangle
    int t = blockIdx.x, I = 0;
    while (t >= NBLK - I) { t -= NBLK - I; ++I; }
    const int J = I + t;
    const bool diag = (I == J);
    const int row0 = I * BM, col0 = J * BN;

    const int tid  = threadIdx.x;
    const int lane = tid & 63;
    const int wid  = tid >> 6;
    const int wr = wid >> 1, wc = wid & 1;
    const int l15 = lane & 15, lq = lane >> 4;

    // staging geometry: segment = 1024B = 8 rows x 64 bf16; 16 segs per tile
    const int srow  = lane >> 3;   // row within segment (0..7)
    const int pslot = lane & 7;    // physical 16B slot within row

    // labels for the 16 rows this lane accumulates
    int lab_r[16];
#pragma unroll
    for (int m = 0; m < 4; ++m)
#pragma unroll
        for (int r = 0; r < 4; ++r)
            lab_r[m * 4 + r] = labels[row0 + wr * 64 + m * 16 + lq * 4 + r];

    f32x4 acc[4][4];
#pragma unroll
    for (int m = 0; m < 4; ++m)
#pragma unroll
        for (int n = 0; n < 4; ++n) acc[m][n] = (f32x4){0.f, 0.f, 0.f, 0.f};

    for (int k0 = 0; k0 < H_DIM; k0 += BK) {
        __syncthreads();   // previous step's LDS reads complete
#pragma unroll
        for (int i = 0; i < 4; ++i) {
            const int seg = wid * 4 + i;
            const int row = seg * 8 + srow;
            const int lslot = pslot ^ (row & 7);   // pre-swizzled source (rule #21)
            async_copy16(&As[seg * 512],
                         &xb[(size_t)(row0 + row) * H_DIM + k0 + lslot * 8]);
            async_copy16(&Bs[seg * 512],
                         &xb[(size_t)(col0 + row) * H_DIM + k0 + lslot * 8]);
        }
        __syncthreads();   // compiler drains vmcnt before s_barrier
#pragma unroll
        for (int kh = 0; kh < 2; ++kh) {
            bf16x8 af[4], bfv[4];
#pragma unroll
            for (int m = 0; m < 4; ++m) {
                const int row = wr * 64 + m * 16 + l15;
                const int ps = (kh * 4 + lq) ^ (row & 7);
                af[m] = *reinterpret_cast<const bf16x8*>(&As[row * 64 + ps * 8]);
            }
#pragma unroll
            for (int n = 0; n < 4; ++n) {
                const int row = wc * 64 + n * 16 + l15;
                const int ps = (kh * 4 + lq) ^ (row & 7);
                bfv[n] = *reinterpret_cast<const bf16x8*>(&Bs[row * 64 + ps * 8]);
            }
#pragma unroll
            for (int m = 0; m < 4; ++m)
#pragma unroll
                for (int n = 0; n < 4; ++n)
                    acc[m][n] = __builtin_amdgcn_mfma_f32_16x16x32_bf16(
                        af[m], bfv[n], acc[m][n], 0, 0, 0);
        }
    }

    // ---- epilogue: exp + masked row sums AND column sums ----
    float rs_pos[16], rs_all[16];
#pragma unroll
    for (int i = 0; i < 16; ++i) { rs_pos[i] = 0.f; rs_all[i] = 0.f; }
    float cs_pos[4], cs_all[4];
#pragma unroll
    for (int n = 0; n < 4; ++n) { cs_pos[n] = 0.f; cs_all[n] = 0.f; }

#pragma unroll
    for (int n = 0; n < 4; ++n) {
        const int colg = col0 + wc * 64 + n * 16 + l15;
        const int lab_c = labels[colg];
#pragma unroll
        for (int m = 0; m < 4; ++m) {
#pragma unroll
            for (int r = 0; r < 4; ++r) {
                const int rowg = row0 + wr * 64 + m * 16 + lq * 4 + r;
                const float e = fast_exp2(acc[m][n][r] * 14.4269504088896340736f);
                const bool self = (rowg == colg);       // only possible when diag
                const bool pos  = (lab_c == lab_r[m * 4 + r]) && !self;
                const float ea = self ? 0.f : e;
                const float ep = pos ? e : 0.f;
                rs_all[m * 4 + r] += ea;
                rs_pos[m * 4 + r] += ep;
                cs_all[n] += ea;
                cs_pos[n] += ep;
            }
        }
    }

    // row partials: reduce across l15 (16-lane groups)
#pragma unroll
    for (int i = 0; i < 16; ++i) {
#pragma unroll
        for (int d = 1; d < 16; d <<= 1) {
            rs_pos[i] += __shfl_xor(rs_pos[i], d, 64);
            rs_all[i] += __shfl_xor(rs_all[i], d, 64);
        }
    }
    // col partials: reduce across lq (lanes differing in bits 4,5)
#pragma unroll
    for (int n = 0; n < 4; ++n) {
#pragma unroll
        for (int d = 16; d < 64; d <<= 1) {
            cs_pos[n] += __shfl_xor(cs_pos[n], d, 64);
            cs_all[n] += __shfl_xor(cs_all[n], d, 64);
        }
    }

    // cross-wave combine via LDS scratch aliased onto As (4 KB of 16 KB)
    __syncthreads();                       // all LDS fragment reads done
    float* sc = (float*)As;
    float* rowpos = sc;                    // [2][128] indexed [wc][localrow]
    float* rowall = sc + 256;
    float* colpos = sc + 512;              // [2][128] indexed [wr][localcol]
    float* colall = sc + 768;
    if (l15 == 0) {
#pragma unroll
        for (int i = 0; i < 16; ++i) {
            const int m = i >> 2, r = i & 3;
            const int lr = wr * 64 + m * 16 + lq * 4 + r;
            rowpos[wc * 128 + lr] = rs_pos[i];
            rowall[wc * 128 + lr] = rs_all[i];
        }
    }
    if (lq == 0 && !diag) {
#pragma unroll
        for (int n = 0; n < 4; ++n) {
            const int lc = wc * 64 + n * 16 + l15;
            colpos[wr * 128 + lc] = cs_pos[n];
            colall[wr * 128 + lc] = cs_all[n];
        }
    }
    __syncthreads();

    // partial-slot scheme: row-side -> slot J, col-side -> slot I.
    // Every (slot s, row i) written exactly once across the triangle.
    if (tid < 128) {
        const float rp = rowpos[tid] + rowpos[128 + tid];
        const float ra = rowall[tid] + rowall[128 + tid];
        ppos[(size_t)J * N_ROWS + row0 + tid] = rp;
        pall[(size_t)J * N_ROWS + row0 + tid] = ra;
    } else if (!diag) {
        const int t2 = tid - 128;
        const float cp = colpos[t2] + colpos[128 + t2];
        const float ca = colall[t2] + colall[128 + t2];
        ppos[(size_t)I * N_ROWS + col0 + t2] = cp;
        pall[(size_t)I * N_ROWS + col0 + t2] = ca;
    }
}

// ---------------- Kernel 3a: per-row loss, per-block partial sums ----------------
__global__ __launch_bounds__(256)
void finalize1_kernel(const int* __restrict__ labels, const float* __restrict__ ppos,
                      const float* __restrict__ pall, float* __restrict__ bsum,
                      int* __restrict__ bcnt) {
    __shared__ int hist[NUM_CLS];
    __shared__ float sred[4];
    __shared__ int scnt[4];
    const int tid = threadIdx.x;
    if (tid < NUM_CLS) hist[tid] = 0;
    __syncthreads();
    for (int i = tid; i < N_ROWS; i += 256) atomicAdd(&hist[labels[i]], 1);
    __syncthreads();

    float lsum = 0.f;
    int vcnt = 0;
    if (tid < 128) {
        const int i = blockIdx.x * 128 + tid;
        float p = 0.f, a = 0.f;
#pragma unroll
        for (int s = 0; s < NBLK; ++s) {
            p += ppos[(size_t)s * N_ROWS + i];
            a += pall[(size_t)s * N_ROWS + i];
        }
        const int cnt = hist[labels[i]] - 1;
        if (cnt > 0) {
            lsum = logf(a) - logf(p) + logf((float)cnt);
            vcnt = 1;
        }
    }
    const int lane = tid & 63, wid = tid >> 6;
#pragma unroll
    for (int d = 1; d < 64; d <<= 1) {
        lsum += __shfl_xor(lsum, d, 64);
        vcnt += __shfl_xor(vcnt, d, 64);
    }
    if (lane == 0) { sred[wid] = lsum; scnt[wid] = vcnt; }
    __syncthreads();
    if (tid == 0) {
        bsum[blockIdx.x] = sred[0] + sred[1] + sred[2] + sred[3];
        bcnt[blockIdx.x] = scnt[0] + scnt[1] + scnt[2] + scnt[3];
    }
}

// ---------------- Kernel 3b: final scalar ----------------
__global__ __launch_bounds__(64)
void finalize2_kernel(const float* __restrict__ bsum, const int* __restrict__ bcnt,
                      float* __restrict__ out) {
    const int tid = threadIdx.x;
    float s = bsum[tid];
    int   c = bcnt[tid];
#pragma unroll
    for (int d = 1; d < 64; d <<= 1) {
        s += __shfl_xor(s, d, 64);
        c += __shfl_xor(c, d, 64);
    }
    if (tid == 0) out[0] = s / (float)c;
}

extern "C" void kernel_launch(void* const* d_in, const int* in_sizes, int n_in,
                              void* d_out, int out_size, void* d_ws, size_t ws_size,
                              hipStream_t stream) {
    const float* emb   = (const float*)d_in[0];
    const int* labels  = (const int*)d_in[1];
    float* out         = (float*)d_out;
    char* ws           = (char*)d_ws;

    ushort* xb  = (ushort*)ws;                                   // 16 MB bf16 normalized
    float* ppos = (float*)(ws + (size_t)N_ROWS * H_DIM * 2);     // NBLK*N floats (2 MB)
    float* pall = ppos + (size_t)NBLK * N_ROWS;                  // NBLK*N floats (2 MB)
    float* bsum = pall + (size_t)NBLK * N_ROWS;                  // 64 floats
    int*   bcnt = (int*)(bsum + NBLK);                           // 64 ints

    norm_kernel<<<N_ROWS, 256, 0, stream>>>(emb, xb);
    simloss_kernel<<<NPAIR, 256, 0, stream>>>(xb, labels, ppos, pall);
    finalize1_kernel<<<NBLK, 256, 0, stream>>>(labels, ppos, pall, bsum, bcnt);
    finalize2_kernel<<<1, 64, 0, stream>>>(bsum, bcnt, out);
}